// Round 6
// baseline (1020.630 us; speedup 1.0000x reference)
//
#include <hip/hip_runtime.h>
#include <cstdint>
#include <cstddef>

// ---------------------------------------------------------------------------
// FCAGAT: 3x GATConv (H=2, C=64) + ELU + concat + MLP(384->128->1)
// Bucketed adjacency build (no global scan, no fine-grained scatter):
//   K1 zeroB      : bktCnt = 0
//   K2 scatter_b  : edge -> bucket(128 dst nodes), pos = atomicAdd(bktCnt),
//                   packed (dLow<<16)|src. Sequential positions per bucket
//                   => L2 write-frontier ~939 lines => full-line evictions.
//   K3 sortbkt    : block/bucket: LDS counting sort by dLow, write bucket
//                   back in place (contiguous) + per-node (start,count).
//   K4 gemm_att   : xw = x@W tiled GEMM (swizzled LDS) + fused att dots
//   K5 aggregate  : wave/node: lane-parallel online softmax + shfl-broadcast
//                   weighted gather of xw[src]
//   K6 final_mlp  : tiled GEMM elu(agg+b)[N,384]@Wc1 + fused relu/Wc2 epilogue
// ---------------------------------------------------------------------------

__device__ __forceinline__ float lrelu02(float x) { return x > 0.f ? x : 0.2f * x; }
__device__ __forceinline__ float elu1(float x) { return x > 0.f ? x : (__expf(x) - 1.f); }

#define TM 64
#define TN 128
#define TKK 32
#define CAP 2816          // bucket capacity (avg 2048, +17 sigma)

// ---------------- K4: XW = X[M,K] @ W[K,128] + fused attention dots ----------
__global__ __launch_bounds__(256) void gemm_att(
    const float* __restrict__ X, const float* __restrict__ W,
    const float* __restrict__ att_s, const float* __restrict__ att_d,
    float* __restrict__ XW, float* __restrict__ a_src, float* __restrict__ a_dst,
    int M, int K) {
  __shared__ __align__(16) float xs[TKK][TM];     // 8 KB, swizzled transposed A
  __shared__ __align__(16) float4 wsB[TKK][TN/4]; // 16 KB, swizzled B
  const int tid = threadIdx.x;
  const int tx = tid & 15;
  const int ty = tid >> 4;
  const int row0 = blockIdx.x * TM;
  float acc[4][8];
#pragma unroll
  for (int r = 0; r < 4; ++r)
#pragma unroll
    for (int c = 0; c < 8; ++c) acc[r][c] = 0.f;

  const int lr = tid >> 2;
  const int lk = (tid & 3) * 8;
  const int wr = tid >> 3;
  const int bb = (tid & 7) * 4;
  const int xcol = lr ^ (((lk >> 3) & 1) * 16);
  const int p0 = (tx * 2) ^ (2 * ((tx * 2) >> 3));
  const int p1 = (tx * 2 + 1) ^ (2 * ((tx * 2 + 1) >> 3));

  for (int k0 = 0; k0 < K; k0 += TKK) {
    int xrow = row0 + lr; if (xrow >= M) xrow = M - 1;
    const float4* xp = (const float4*)(X + (size_t)xrow * K + k0 + lk);
    float4 xa = xp[0];
    float4 xb = xp[1];
    const float4* wp = (const float4*)(W + (size_t)(k0 + wr) * TN + bb * 4);
    float4 w0 = wp[0], w1 = wp[1], w2 = wp[2], w3 = wp[3];
    __syncthreads();
    xs[lk + 0][xcol] = xa.x; xs[lk + 1][xcol] = xa.y;
    xs[lk + 2][xcol] = xa.z; xs[lk + 3][xcol] = xa.w;
    xs[lk + 4][xcol] = xb.x; xs[lk + 5][xcol] = xb.y;
    xs[lk + 6][xcol] = xb.z; xs[lk + 7][xcol] = xb.w;
    {
      int b0i = bb + 0; wsB[wr][b0i ^ (2 * (b0i >> 3))] = w0;
      int b1i = bb + 1; wsB[wr][b1i ^ (2 * (b1i >> 3))] = w1;
      int b2i = bb + 2; wsB[wr][b2i ^ (2 * (b2i >> 3))] = w2;
      int b3i = bb + 3; wsB[wr][b3i ^ (2 * (b3i >> 3))] = w3;
    }
    __syncthreads();
#pragma unroll
    for (int k = 0; k < TKK; ++k) {
      const int acol = (ty * 4) ^ (((k >> 3) & 1) * 16);
      float4 a = *(const float4*)&xs[k][acol];
      float4 b0 = wsB[k][p0];
      float4 b1 = wsB[k][p1];
      float av[4] = {a.x, a.y, a.z, a.w};
      float bv[8] = {b0.x, b0.y, b0.z, b0.w, b1.x, b1.y, b1.z, b1.w};
#pragma unroll
      for (int r = 0; r < 4; ++r)
#pragma unroll
        for (int c = 0; c < 8; ++c)
          acc[r][c] = fmaf(av[r], bv[c], acc[r][c]);
    }
  }
#pragma unroll
  for (int r = 0; r < 4; ++r) {
    int row = row0 + ty * 4 + r;
    if (row < M) {
      float4 o0 = {acc[r][0], acc[r][1], acc[r][2], acc[r][3]};
      float4 o1 = {acc[r][4], acc[r][5], acc[r][6], acc[r][7]};
      float4* op = (float4*)(XW + (size_t)row * TN + tx * 8);
      op[0] = o0; op[1] = o1;
    }
  }
  // fused attention dots: this thread's 8 cols all belong to head tx>>3
  float ps[4] = {0.f, 0.f, 0.f, 0.f}, pd[4] = {0.f, 0.f, 0.f, 0.f};
#pragma unroll
  for (int c = 0; c < 8; ++c) {
    float as = att_s[tx * 8 + c], ad = att_d[tx * 8 + c];
#pragma unroll
    for (int r = 0; r < 4; ++r) {
      ps[r] = fmaf(acc[r][c], as, ps[r]);
      pd[r] = fmaf(acc[r][c], ad, pd[r]);
    }
  }
#pragma unroll
  for (int off = 1; off < 8; off <<= 1) {
#pragma unroll
    for (int r = 0; r < 4; ++r) {
      ps[r] += __shfl_xor(ps[r], off);
      pd[r] += __shfl_xor(pd[r], off);
    }
  }
  if ((tx & 7) == 0) {
    int head = tx >> 3;
#pragma unroll
    for (int r = 0; r < 4; ++r) {
      int row = row0 + ty * 4 + r;
      if (row < M) {
        a_src[row * 2 + head] = ps[r];
        a_dst[row * 2 + head] = pd[r];
      }
    }
  }
}

// ---------------- K1: zero bucket counters ----------------
__global__ void zeroB(int* __restrict__ a, int n) {
  int i = blockIdx.x * blockDim.x + threadIdx.x;
  if (i < n) a[i] = 0;
}

// ---------------- K2: bucketed edge scatter ----------------
__global__ void scatter_b(const int* __restrict__ ei0, const int* __restrict__ ei1,
                          const int* __restrict__ ei2, int E0, int E1, int E2,
                          int Nn, int nbpc, int* __restrict__ bktCnt,
                          int* __restrict__ bkt) {
  int i = blockIdx.x * blockDim.x + threadIdx.x;
  int c1 = E0, c2 = E0 + E1, totE = c2 + E2, tot = totE + 3 * Nn;
  if (i >= tot) return;
  int s, d, cat;
  if (i < totE) {
    if (i < c1)      { s = ei0[i];            d = ei0[E0 + i];      cat = 0; }
    else if (i < c2) { int t = i - c1; s = ei1[t]; d = ei1[E1 + t]; cat = 1; }
    else             { int t = i - c2; s = ei2[t]; d = ei2[E2 + t]; cat = 2; }
  } else {
    int j = i - totE;
    cat = (j < Nn) ? 0 : (j < 2 * Nn) ? 1 : 2;
    int n = j - cat * Nn;
    s = n; d = n;
  }
  int b = cat * nbpc + (d >> 7);
  int pos = atomicAdd(&bktCnt[b], 1);
  if (pos < CAP) bkt[(size_t)b * CAP + pos] = ((d & 127) << 16) | s;
}

// ---------------- K3: per-bucket LDS counting sort + (start,count) ----------
__global__ __launch_bounds__(256) void sortbkt(
    int* __restrict__ bkt, const int* __restrict__ bktCnt,
    int2* __restrict__ offcnt, int Nn, int nbpc) {
  __shared__ int cntA[128], scanA[128], fillA[128];
  __shared__ int esort[CAP];
  const int tid = threadIdx.x;
  const int b = blockIdx.x;
  const int cat = b / nbpc, bl = b - cat * nbpc, dBase = bl << 7;
  const int cnt = min(bktCnt[b], CAP);
  int* mybkt = bkt + (size_t)b * CAP;
  if (tid < 128) { cntA[tid] = 0; fillA[tid] = 0; }
  __syncthreads();
  for (int i = tid; i < cnt; i += 256) atomicAdd(&cntA[mybkt[i] >> 16], 1);
  __syncthreads();
  if (tid < 128) scanA[tid] = cntA[tid];
  __syncthreads();
  for (int off = 1; off < 128; off <<= 1) {
    int t = (tid < 128 && tid >= off) ? scanA[tid - off] : 0;
    __syncthreads();
    if (tid < 128) scanA[tid] += t;
    __syncthreads();
  }
  // exclusive start for node t = scanA[t] - cntA[t]
  for (int i = tid; i < cnt; i += 256) {
    int v = mybkt[i];
    int n = v >> 16;
    int p = scanA[n] - cntA[n] + atomicAdd(&fillA[n], 1);
    esort[p] = v & 0xFFFF;
  }
  __syncthreads();
  for (int i = tid; i < cnt; i += 256) mybkt[i] = esort[i];
  if (tid < 128 && dBase + tid < Nn)
    offcnt[(size_t)cat * Nn + dBase + tid] =
        make_int2(b * CAP + scanA[tid] - cntA[tid], cntA[tid]);
}

// ---------------- K5: lane-parallel segment softmax + gather ----------------
__global__ __launch_bounds__(256) void aggregate(
    const float* __restrict__ xw, const float* __restrict__ a_src,
    const float* __restrict__ a_dst, const int2* __restrict__ offcnt,
    const int* __restrict__ adjS, float* __restrict__ agg, int Nn) {
  const int node = (int)((blockIdx.x * (size_t)blockDim.x + threadIdx.x) >> 6);
  const int lane = threadIdx.x & 63;
  if (node >= Nn) return;
  const int2 oc = offcnt[node];
  const int base = oc.x, end = oc.x + oc.y;
  const float2 ad = ((const float2*)a_dst)[node];

  // phase 1: lane-strided online softmax stats; keep first chunk in regs
  float m0 = -1e30f, s0 = 0.f, m1 = -1e30f, s1 = 0.f;
  int sv0 = 0; float ex0 = -1e30f, ey0 = -1e30f;
  for (int cb = base; cb < end; cb += 64) {
    int j = cb + lane;
    int sv = 0; float ex = -1e30f, ey = -1e30f;
    if (j < end) {
      sv = adjS[j];
      float2 as = ((const float2*)a_src)[sv];
      ex = lrelu02(as.x + ad.x);
      ey = lrelu02(as.y + ad.y);
      float nm0 = fmaxf(m0, ex);
      s0 = s0 * __expf(m0 - nm0) + __expf(ex - nm0); m0 = nm0;
      float nm1 = fmaxf(m1, ey);
      s1 = s1 * __expf(m1 - nm1) + __expf(ey - nm1); m1 = nm1;
    }
    if (cb == base) { sv0 = sv; ex0 = ex; ey0 = ey; }
  }
#pragma unroll
  for (int off = 32; off; off >>= 1) {
    float om0 = __shfl_xor(m0, off), os0 = __shfl_xor(s0, off);
    float nm0 = fmaxf(m0, om0);
    s0 = s0 * __expf(m0 - nm0) + os0 * __expf(om0 - nm0); m0 = nm0;
    float om1 = __shfl_xor(m1, off), os1 = __shfl_xor(s1, off);
    float nm1 = fmaxf(m1, om1);
    s1 = s1 * __expf(m1 - nm1) + os1 * __expf(om1 - nm1); m1 = nm1;
  }
  const float inv0 = 1.f / s0, inv1 = 1.f / s1;

  // phase 2: weight once per edge (its lane), shfl-broadcast, gather x4
  float acc0 = 0.f, acc1 = 0.f;
  for (int cb = base; cb < end; cb += 64) {
    const int cnt = min(64, end - cb);
    int srcv; float w0v, w1v;
    if (cb == base) {
      srcv = sv0;
      w0v = __expf(ex0 - m0) * inv0;   // inactive lanes: exp(-inf)=0
      w1v = __expf(ey0 - m1) * inv1;
    } else {
      srcv = 0; float ex = -1e30f, ey = -1e30f;
      if (lane < cnt) {
        srcv = adjS[cb + lane];
        float2 as = ((const float2*)a_src)[srcv];
        ex = lrelu02(as.x + ad.x);
        ey = lrelu02(as.y + ad.y);
      }
      w0v = __expf(ex - m0) * inv0;
      w1v = __expf(ey - m1) * inv1;
    }
    int k = 0;
    for (; k + 4 <= cnt; k += 4) {
      int sa = __shfl(srcv, k),     sb = __shfl(srcv, k + 1);
      int sc = __shfl(srcv, k + 2), sd = __shfl(srcv, k + 3);
      float wa0 = __shfl(w0v, k),     wb0 = __shfl(w0v, k + 1);
      float wc0 = __shfl(w0v, k + 2), wd0 = __shfl(w0v, k + 3);
      float wa1 = __shfl(w1v, k),     wb1 = __shfl(w1v, k + 1);
      float wc1 = __shfl(w1v, k + 2), wd1 = __shfl(w1v, k + 3);
      const float* pa = xw + (size_t)sa * 128 + lane;
      const float* pb = xw + (size_t)sb * 128 + lane;
      const float* pc = xw + (size_t)sc * 128 + lane;
      const float* pd = xw + (size_t)sd * 128 + lane;
      float xa0 = pa[0], xa1 = pa[64];
      float xb0 = pb[0], xb1 = pb[64];
      float xc0 = pc[0], xc1 = pc[64];
      float xd0 = pd[0], xd1 = pd[64];
      acc0 = fmaf(wa0, xa0, acc0); acc1 = fmaf(wa1, xa1, acc1);
      acc0 = fmaf(wb0, xb0, acc0); acc1 = fmaf(wb1, xb1, acc1);
      acc0 = fmaf(wc0, xc0, acc0); acc1 = fmaf(wc1, xc1, acc1);
      acc0 = fmaf(wd0, xd0, acc0); acc1 = fmaf(wd1, xd1, acc1);
    }
    for (; k < cnt; ++k) {
      int s = __shfl(srcv, k);
      float w0 = __shfl(w0v, k);
      float w1 = __shfl(w1v, k);
      const float* p = xw + (size_t)s * 128 + lane;
      acc0 = fmaf(w0, p[0], acc0);
      acc1 = fmaf(w1, p[64], acc1);
    }
  }
  agg[(size_t)node * 128 + lane] = acc0;
  agg[(size_t)node * 128 + 64 + lane] = acc1;
}

// ---------------- K6: final MLP as tiled GEMM, swizzled LDS ----------------
__global__ __launch_bounds__(256) void final_mlp(
    const float* __restrict__ agg0, const float* __restrict__ agg1,
    const float* __restrict__ agg2, const float* __restrict__ bias0,
    const float* __restrict__ bias1, const float* __restrict__ bias2,
    const float* __restrict__ Wc1, const float* __restrict__ bc1,
    const float* __restrict__ Wc2, const float* __restrict__ bc2,
    float* __restrict__ out, int Nn) {
  __shared__ __align__(16) float xs[TKK][TM];
  __shared__ __align__(16) float4 wsB[TKK][TN/4];
  __shared__ float red[TM][17];
  const int tid = threadIdx.x;
  const int tx = tid & 15;
  const int ty = tid >> 4;
  const int row0 = blockIdx.x * TM;
  float acc[4][8];
#pragma unroll
  for (int r = 0; r < 4; ++r)
#pragma unroll
    for (int c = 0; c < 8; ++c) acc[r][c] = 0.f;

  const int lr = tid >> 2;
  const int lk = (tid & 3) * 8;
  const int wr = tid >> 3;
  const int bb = (tid & 7) * 4;
  const int xcol = lr ^ (((lk >> 3) & 1) * 16);
  const int p0 = (tx * 2) ^ (2 * ((tx * 2) >> 3));
  const int p1 = (tx * 2 + 1) ^ (2 * ((tx * 2 + 1) >> 3));

  for (int k0 = 0; k0 < 384; k0 += TKK) {
    int row = row0 + lr; if (row >= Nn) row = Nn - 1;
    const int kg = k0 + lk;
    const int sel = kg >> 7, q = kg & 127;
    const float* aggp = (sel == 0) ? agg0 : (sel == 1) ? agg1 : agg2;
    const float* bp   = (sel == 0) ? bias0 : (sel == 1) ? bias1 : bias2;
    float4 xa = *(const float4*)(aggp + (size_t)row * 128 + q);
    float4 xb = *(const float4*)(aggp + (size_t)row * 128 + q + 4);
    float4 ba = *(const float4*)(bp + q);
    float4 bbv = *(const float4*)(bp + q + 4);
    xa.x = elu1(xa.x + ba.x); xa.y = elu1(xa.y + ba.y);
    xa.z = elu1(xa.z + ba.z); xa.w = elu1(xa.w + ba.w);
    xb.x = elu1(xb.x + bbv.x); xb.y = elu1(xb.y + bbv.y);
    xb.z = elu1(xb.z + bbv.z); xb.w = elu1(xb.w + bbv.w);
    const float4* wp = (const float4*)(Wc1 + (size_t)(k0 + wr) * TN + bb * 4);
    float4 w0 = wp[0], w1 = wp[1], w2 = wp[2], w3 = wp[3];
    __syncthreads();
    xs[lk + 0][xcol] = xa.x; xs[lk + 1][xcol] = xa.y;
    xs[lk + 2][xcol] = xa.z; xs[lk + 3][xcol] = xa.w;
    xs[lk + 4][xcol] = xb.x; xs[lk + 5][xcol] = xb.y;
    xs[lk + 6][xcol] = xb.z; xs[lk + 7][xcol] = xb.w;
    {
      int b0i = bb + 0; wsB[wr][b0i ^ (2 * (b0i >> 3))] = w0;
      int b1i = bb + 1; wsB[wr][b1i ^ (2 * (b1i >> 3))] = w1;
      int b2i = bb + 2; wsB[wr][b2i ^ (2 * (b2i >> 3))] = w2;
      int b3i = bb + 3; wsB[wr][b3i ^ (2 * (b3i >> 3))] = w3;
    }
    __syncthreads();
#pragma unroll
    for (int k = 0; k < TKK; ++k) {
      const int acol = (ty * 4) ^ (((k >> 3) & 1) * 16);
      float4 a = *(const float4*)&xs[k][acol];
      float4 b0 = wsB[k][p0];
      float4 b1 = wsB[k][p1];
      float av[4] = {a.x, a.y, a.z, a.w};
      float bv[8] = {b0.x, b0.y, b0.z, b0.w, b1.x, b1.y, b1.z, b1.w};
#pragma unroll
      for (int r = 0; r < 4; ++r)
#pragma unroll
        for (int c = 0; c < 8; ++c)
          acc[r][c] = fmaf(av[r], bv[c], acc[r][c]);
    }
  }

  float bcv[8], w2v[8];
#pragma unroll
  for (int c = 0; c < 8; ++c) {
    bcv[c] = bc1[tx * 8 + c];
    w2v[c] = Wc2[tx * 8 + c];
  }
#pragma unroll
  for (int r = 0; r < 4; ++r) {
    float p = 0.f;
#pragma unroll
    for (int c = 0; c < 8; ++c)
      p = fmaf(fmaxf(acc[r][c] + bcv[c], 0.f), w2v[c], p);
    red[ty * 4 + r][tx] = p;
  }
  __syncthreads();
  if (tid < TM) {
    float s = 0.f;
#pragma unroll
    for (int i = 0; i < 16; ++i) s += red[tid][i];
    int n = row0 + tid;
    if (n < Nn) out[n] = s + bc2[0];
  }
}

// ---------------------------------------------------------------------------
extern "C" void kernel_launch(void* const* d_in, const int* in_sizes, int n_in,
                              void* d_out, int out_size, void* d_ws, size_t ws_size,
                              hipStream_t stream) {
  const int Nn = out_size;            // 40000
  const int E0 = in_sizes[1] / 2;
  const int E1 = in_sizes[7] / 2;
  const int E2 = in_sizes[13] / 2;
  const int totE = E0 + E1 + E2;
  const int Nt = 3 * Nn;
  const int nbpc = (Nn + 127) / 128;  // buckets per category
  const int NB = 3 * nbpc;

  char* base = (char*)d_ws;
  size_t off = 0;
  auto carve = [&](size_t bytes) -> void* {
    off = (off + 255) & ~(size_t)255;
    void* p = base + off;
    off += bytes;
    return p;
  };
  float* xw     = (float*)carve((size_t)Nn * 128 * 4);      // reused per cat
  float* agg3   = (float*)carve((size_t)Nt * 128 * 4);
  float* a_src3 = (float*)carve((size_t)Nt * 2 * 4);
  float* a_dst3 = (float*)carve((size_t)Nt * 2 * 4);
  int*  bktCnt  = (int*)carve((size_t)NB * 4);
  int2* offcnt3 = (int2*)carve((size_t)Nt * 8);
  int*  bkt     = (int*)carve((size_t)NB * CAP * 4);
  (void)ws_size; (void)n_in;

  const int* ei0 = (const int*)d_in[1];
  const int* ei1 = (const int*)d_in[7];
  const int* ei2 = (const int*)d_in[13];

  // bucketed adjacency build
  zeroB<<<(NB + 255) / 256, 256, 0, stream>>>(bktCnt, NB);
  scatter_b<<<(totE + Nt + 255) / 256, 256, 0, stream>>>(
      ei0, ei1, ei2, E0, E1, E2, Nn, nbpc, bktCnt, bkt);
  sortbkt<<<NB, 256, 0, stream>>>(bkt, bktCnt, offcnt3, Nn, nbpc);

  for (int cat = 0; cat < 3; ++cat) {
    const float* x   = (const float*)d_in[6 * cat + 0];
    const float* W   = (const float*)d_in[6 * cat + 2];
    const float* ats = (const float*)d_in[6 * cat + 3];
    const float* atd = (const float*)d_in[6 * cat + 4];
    const int K = in_sizes[6 * cat] / Nn;
    float* a_src_c = a_src3 + (size_t)cat * Nn * 2;
    float* a_dst_c = a_dst3 + (size_t)cat * Nn * 2;

    gemm_att<<<(Nn + TM - 1) / TM, 256, 0, stream>>>(
        x, W, ats, atd, xw, a_src_c, a_dst_c, Nn, K);
    aggregate<<<((size_t)Nn * 64 + 255) / 256, 256, 0, stream>>>(
        xw, a_src_c, a_dst_c, offcnt3 + (size_t)cat * Nn, bkt,
        agg3 + (size_t)cat * Nn * 128, Nn);
  }

  final_mlp<<<(Nn + TM - 1) / TM, 256, 0, stream>>>(
      agg3, agg3 + (size_t)Nn * 128, agg3 + (size_t)2 * Nn * 128,
      (const float*)d_in[5], (const float*)d_in[11], (const float*)d_in[17],
      (const float*)d_in[18], (const float*)d_in[19],
      (const float*)d_in[20], (const float*)d_in[21],
      (float*)d_out, Nn);
}

// Round 8
// 494.009 us; speedup vs baseline: 2.0660x; 2.0660x over previous
//
#include <hip/hip_runtime.h>
#include <cstdint>
#include <cstddef>

// ---------------------------------------------------------------------------
// FCAGAT: 3x GATConv (H=2, C=64) + ELU + concat + MLP(384->128->1)
// Bucketed adjacency build with XCD-PRIVATE slices (R6: same-line atomics
// across XCDs serialize ~300 ns/op via line migration; XCD-local pipeline).
// R7 fix: self-loops spread across slices via (n>>4)&7 (was blockIdx&7 which
// clumped all 128 of a bucket's self-loops into ONE cell -> CAPX overflow ->
// silently dropped edges -> absmax 0.235). CAPX 384->448 (+12 sigma).
//   K1 zeroB      : bktCnt = 0   (one counter per 64B line)
//   K2 scatter_b  : edge -> (bucket of 128 dst nodes, slice), pos =
//                   atomicAdd(XCD-private counter), packed (dLow<<16)|src
//   K3 sortbkt    : block/bucket: read 8 slices, LDS counting sort by dLow,
//                   compact in place + per-node (start,count).
//   K4 gemm_att   : xw = x@W tiled GEMM (swizzled LDS) + fused att dots
//   K5 aggregate  : wave/node: lane-parallel online softmax + shfl-broadcast
//                   weighted gather of xw[src]
//   K6 final_mlp  : tiled GEMM elu(agg+b)[N,384]@Wc1 + fused relu/Wc2 epilogue
// ---------------------------------------------------------------------------

__device__ __forceinline__ float lrelu02(float x) { return x > 0.f ? x : 0.2f * x; }
__device__ __forceinline__ float elu1(float x) { return x > 0.f ? x : (__expf(x) - 1.f); }

#define TM 64
#define TN 128
#define TKK 32
#define SLICES 8
#define CAPX 448               // per-(bucket,slice): mean ~256, +12 sigma
#define BCAP (SLICES * CAPX)   // 3584 >= max bucket total (~2046)

// ---------------- K4: XW = X[M,K] @ W[K,128] + fused attention dots ----------
__global__ __launch_bounds__(256) void gemm_att(
    const float* __restrict__ X, const float* __restrict__ W,
    const float* __restrict__ att_s, const float* __restrict__ att_d,
    float* __restrict__ XW, float* __restrict__ a_src, float* __restrict__ a_dst,
    int M, int K) {
  __shared__ __align__(16) float xs[TKK][TM];     // 8 KB, swizzled transposed A
  __shared__ __align__(16) float4 wsB[TKK][TN/4]; // 16 KB, swizzled B
  const int tid = threadIdx.x;
  const int tx = tid & 15;
  const int ty = tid >> 4;
  const int row0 = blockIdx.x * TM;
  float acc[4][8];
#pragma unroll
  for (int r = 0; r < 4; ++r)
#pragma unroll
    for (int c = 0; c < 8; ++c) acc[r][c] = 0.f;

  const int lr = tid >> 2;
  const int lk = (tid & 3) * 8;
  const int wr = tid >> 3;
  const int bb = (tid & 7) * 4;
  const int xcol = lr ^ (((lk >> 3) & 1) * 16);
  const int p0 = (tx * 2) ^ (2 * ((tx * 2) >> 3));
  const int p1 = (tx * 2 + 1) ^ (2 * ((tx * 2 + 1) >> 3));

  for (int k0 = 0; k0 < K; k0 += TKK) {
    int xrow = row0 + lr; if (xrow >= M) xrow = M - 1;
    const float4* xp = (const float4*)(X + (size_t)xrow * K + k0 + lk);
    float4 xa = xp[0];
    float4 xb = xp[1];
    const float4* wp = (const float4*)(W + (size_t)(k0 + wr) * TN + bb * 4);
    float4 w0 = wp[0], w1 = wp[1], w2 = wp[2], w3 = wp[3];
    __syncthreads();
    xs[lk + 0][xcol] = xa.x; xs[lk + 1][xcol] = xa.y;
    xs[lk + 2][xcol] = xa.z; xs[lk + 3][xcol] = xa.w;
    xs[lk + 4][xcol] = xb.x; xs[lk + 5][xcol] = xb.y;
    xs[lk + 6][xcol] = xb.z; xs[lk + 7][xcol] = xb.w;
    {
      int b0i = bb + 0; wsB[wr][b0i ^ (2 * (b0i >> 3))] = w0;
      int b1i = bb + 1; wsB[wr][b1i ^ (2 * (b1i >> 3))] = w1;
      int b2i = bb + 2; wsB[wr][b2i ^ (2 * (b2i >> 3))] = w2;
      int b3i = bb + 3; wsB[wr][b3i ^ (2 * (b3i >> 3))] = w3;
    }
    __syncthreads();
#pragma unroll
    for (int k = 0; k < TKK; ++k) {
      const int acol = (ty * 4) ^ (((k >> 3) & 1) * 16);
      float4 a = *(const float4*)&xs[k][acol];
      float4 b0 = wsB[k][p0];
      float4 b1 = wsB[k][p1];
      float av[4] = {a.x, a.y, a.z, a.w};
      float bv[8] = {b0.x, b0.y, b0.z, b0.w, b1.x, b1.y, b1.z, b1.w};
#pragma unroll
      for (int r = 0; r < 4; ++r)
#pragma unroll
        for (int c = 0; c < 8; ++c)
          acc[r][c] = fmaf(av[r], bv[c], acc[r][c]);
    }
  }
#pragma unroll
  for (int r = 0; r < 4; ++r) {
    int row = row0 + ty * 4 + r;
    if (row < M) {
      float4 o0 = {acc[r][0], acc[r][1], acc[r][2], acc[r][3]};
      float4 o1 = {acc[r][4], acc[r][5], acc[r][6], acc[r][7]};
      float4* op = (float4*)(XW + (size_t)row * TN + tx * 8);
      op[0] = o0; op[1] = o1;
    }
  }
  // fused attention dots: this thread's 8 cols all belong to head tx>>3
  float ps[4] = {0.f, 0.f, 0.f, 0.f}, pd[4] = {0.f, 0.f, 0.f, 0.f};
#pragma unroll
  for (int c = 0; c < 8; ++c) {
    float as = att_s[tx * 8 + c], ad = att_d[tx * 8 + c];
#pragma unroll
    for (int r = 0; r < 4; ++r) {
      ps[r] = fmaf(acc[r][c], as, ps[r]);
      pd[r] = fmaf(acc[r][c], ad, pd[r]);
    }
  }
#pragma unroll
  for (int off = 1; off < 8; off <<= 1) {
#pragma unroll
    for (int r = 0; r < 4; ++r) {
      ps[r] += __shfl_xor(ps[r], off);
      pd[r] += __shfl_xor(pd[r], off);
    }
  }
  if ((tx & 7) == 0) {
    int head = tx >> 3;
#pragma unroll
    for (int r = 0; r < 4; ++r) {
      int row = row0 + ty * 4 + r;
      if (row < M) {
        a_src[row * 2 + head] = ps[r];
        a_dst[row * 2 + head] = pd[r];
      }
    }
  }
}

// ---------------- K1: zero (line-padded) bucket counters ----------------
__global__ void zeroB(int* __restrict__ a, int n) {
  int i = blockIdx.x * blockDim.x + threadIdx.x;
  if (i < n) a[i] = 0;
}

// ---------------- K2: bucketed edge scatter, XCD-private slices ----------
__global__ void scatter_b(const int* __restrict__ ei0, const int* __restrict__ ei1,
                          const int* __restrict__ ei2, int E0, int E1, int E2,
                          int Nn, int nbpc, int* __restrict__ bktCnt,
                          int* __restrict__ bkt) {
  int i = blockIdx.x * blockDim.x + threadIdx.x;
  int c1 = E0, c2 = E0 + E1, totE = c2 + E2, tot = totE + 3 * Nn;
  if (i >= tot) return;
  int s, d, cat, slice;
  if (i < totE) {
    if (i < c1)      { s = ei0[i];            d = ei0[E0 + i];      cat = 0; }
    else if (i < c2) { int t = i - c1; s = ei1[t]; d = ei1[E1 + t]; cat = 1; }
    else             { int t = i - c2; s = ei2[t]; d = ei2[E2 + t]; cat = 2; }
    slice = blockIdx.x & (SLICES - 1);    // ~= XCD id (round-robin dispatch)
  } else {
    int j = i - totE;
    cat = (j < Nn) ? 0 : (j < 2 * Nn) ? 1 : 2;
    int n = j - cat * Nn;
    s = n; d = n;
    slice = (n >> 4) & (SLICES - 1);      // spread self-loops: 16 per cell
  }
  const int bs = (cat * nbpc + (d >> 7)) * SLICES + slice;
  int pos = atomicAdd(&bktCnt[bs * 16], 1);       // 1 counter per 64B line
  if (pos < CAPX) bkt[(size_t)bs * CAPX + pos] = ((d & 127) << 16) | s;
}

// ---------------- K3: merge slices, LDS counting sort, compact in place -----
__global__ __launch_bounds__(256) void sortbkt(
    int* __restrict__ bkt, const int* __restrict__ bktCnt,
    int2* __restrict__ offcnt, int Nn, int nbpc) {
  __shared__ int cntA[128], scanA[128], fillA[128];
  __shared__ int esort[BCAP];
  const int tid = threadIdx.x;
  const int b = blockIdx.x;
  const int cat = b / nbpc, bl = b - cat * nbpc, dBase = bl << 7;
  if (tid < 128) { cntA[tid] = 0; fillA[tid] = 0; }
  __syncthreads();
  int ns[SLICES];
#pragma unroll
  for (int s = 0; s < SLICES; ++s)
    ns[s] = min(bktCnt[(b * SLICES + s) * 16], CAPX);
  // pass 1: histogram by dLow
#pragma unroll
  for (int s = 0; s < SLICES; ++s) {
    const int* seg = bkt + (size_t)(b * SLICES + s) * CAPX;
    for (int i = tid; i < ns[s]; i += 256) atomicAdd(&cntA[seg[i] >> 16], 1);
  }
  __syncthreads();
  if (tid < 128) scanA[tid] = cntA[tid];
  __syncthreads();
  for (int off = 1; off < 128; off <<= 1) {
    int t = (tid < 128 && tid >= off) ? scanA[tid - off] : 0;
    __syncthreads();
    if (tid < 128) scanA[tid] += t;
    __syncthreads();
  }
  // pass 2: place (exclusive start for node t = scanA[t]-cntA[t])
#pragma unroll
  for (int s = 0; s < SLICES; ++s) {
    const int* seg = bkt + (size_t)(b * SLICES + s) * CAPX;
    for (int i = tid; i < ns[s]; i += 256) {
      int v = seg[i];
      int n = v >> 16;
      int p = scanA[n] - cntA[n] + atomicAdd(&fillA[n], 1);
      esort[p] = v & 0xFFFF;
    }
  }
  __syncthreads();
  const int tot = scanA[127];
  int* outp = bkt + (size_t)b * BCAP;     // compact to bucket base
  for (int i = tid; i < tot; i += 256) outp[i] = esort[i];
  if (tid < 128 && dBase + tid < Nn)
    offcnt[(size_t)cat * Nn + dBase + tid] =
        make_int2(b * BCAP + scanA[tid] - cntA[tid], cntA[tid]);
}

// ---------------- K5: lane-parallel segment softmax + gather ----------------
__global__ __launch_bounds__(256) void aggregate(
    const float* __restrict__ xw, const float* __restrict__ a_src,
    const float* __restrict__ a_dst, const int2* __restrict__ offcnt,
    const int* __restrict__ adjS, float* __restrict__ agg, int Nn) {
  const int node = (int)((blockIdx.x * (size_t)blockDim.x + threadIdx.x) >> 6);
  const int lane = threadIdx.x & 63;
  if (node >= Nn) return;
  const int2 oc = offcnt[node];
  const int base = oc.x, end = oc.x + oc.y;
  const float2 ad = ((const float2*)a_dst)[node];

  // phase 1: lane-strided online softmax stats; keep first chunk in regs
  float m0 = -1e30f, s0 = 0.f, m1 = -1e30f, s1 = 0.f;
  int sv0 = 0; float ex0 = -1e30f, ey0 = -1e30f;
  for (int cb = base; cb < end; cb += 64) {
    int j = cb + lane;
    int sv = 0; float ex = -1e30f, ey = -1e30f;
    if (j < end) {
      sv = adjS[j];
      float2 as = ((const float2*)a_src)[sv];
      ex = lrelu02(as.x + ad.x);
      ey = lrelu02(as.y + ad.y);
      float nm0 = fmaxf(m0, ex);
      s0 = s0 * __expf(m0 - nm0) + __expf(ex - nm0); m0 = nm0;
      float nm1 = fmaxf(m1, ey);
      s1 = s1 * __expf(m1 - nm1) + __expf(ey - nm1); m1 = nm1;
    }
    if (cb == base) { sv0 = sv; ex0 = ex; ey0 = ey; }
  }
#pragma unroll
  for (int off = 32; off; off >>= 1) {
    float om0 = __shfl_xor(m0, off), os0 = __shfl_xor(s0, off);
    float nm0 = fmaxf(m0, om0);
    s0 = s0 * __expf(m0 - nm0) + os0 * __expf(om0 - nm0); m0 = nm0;
    float om1 = __shfl_xor(m1, off), os1 = __shfl_xor(s1, off);
    float nm1 = fmaxf(m1, om1);
    s1 = s1 * __expf(m1 - nm1) + os1 * __expf(om1 - nm1); m1 = nm1;
  }
  const float inv0 = 1.f / s0, inv1 = 1.f / s1;

  // phase 2: weight once per edge (its lane), shfl-broadcast, gather x4
  float acc0 = 0.f, acc1 = 0.f;
  for (int cb = base; cb < end; cb += 64) {
    const int cnt = min(64, end - cb);
    int srcv; float w0v, w1v;
    if (cb == base) {
      srcv = sv0;
      w0v = __expf(ex0 - m0) * inv0;   // inactive lanes: exp(-inf)=0
      w1v = __expf(ey0 - m1) * inv1;
    } else {
      srcv = 0; float ex = -1e30f, ey = -1e30f;
      if (lane < cnt) {
        srcv = adjS[cb + lane];
        float2 as = ((const float2*)a_src)[srcv];
        ex = lrelu02(as.x + ad.x);
        ey = lrelu02(as.y + ad.y);
      }
      w0v = __expf(ex - m0) * inv0;
      w1v = __expf(ey - m1) * inv1;
    }
    int k = 0;
    for (; k + 4 <= cnt; k += 4) {
      int sa = __shfl(srcv, k),     sb = __shfl(srcv, k + 1);
      int sc = __shfl(srcv, k + 2), sd = __shfl(srcv, k + 3);
      float wa0 = __shfl(w0v, k),     wb0 = __shfl(w0v, k + 1);
      float wc0 = __shfl(w0v, k + 2), wd0 = __shfl(w0v, k + 3);
      float wa1 = __shfl(w1v, k),     wb1 = __shfl(w1v, k + 1);
      float wc1 = __shfl(w1v, k + 2), wd1 = __shfl(w1v, k + 3);
      const float* pa = xw + (size_t)sa * 128 + lane;
      const float* pb = xw + (size_t)sb * 128 + lane;
      const float* pc = xw + (size_t)sc * 128 + lane;
      const float* pd = xw + (size_t)sd * 128 + lane;
      float xa0 = pa[0], xa1 = pa[64];
      float xb0 = pb[0], xb1 = pb[64];
      float xc0 = pc[0], xc1 = pc[64];
      float xd0 = pd[0], xd1 = pd[64];
      acc0 = fmaf(wa0, xa0, acc0); acc1 = fmaf(wa1, xa1, acc1);
      acc0 = fmaf(wb0, xb0, acc0); acc1 = fmaf(wb1, xb1, acc1);
      acc0 = fmaf(wc0, xc0, acc0); acc1 = fmaf(wc1, xc1, acc1);
      acc0 = fmaf(wd0, xd0, acc0); acc1 = fmaf(wd1, xd1, acc1);
    }
    for (; k < cnt; ++k) {
      int s = __shfl(srcv, k);
      float w0 = __shfl(w0v, k);
      float w1 = __shfl(w1v, k);
      const float* p = xw + (size_t)s * 128 + lane;
      acc0 = fmaf(w0, p[0], acc0);
      acc1 = fmaf(w1, p[64], acc1);
    }
  }
  agg[(size_t)node * 128 + lane] = acc0;
  agg[(size_t)node * 128 + 64 + lane] = acc1;
}

// ---------------- K6: final MLP as tiled GEMM, swizzled LDS ----------------
__global__ __launch_bounds__(256) void final_mlp(
    const float* __restrict__ agg0, const float* __restrict__ agg1,
    const float* __restrict__ agg2, const float* __restrict__ bias0,
    const float* __restrict__ bias1, const float* __restrict__ bias2,
    const float* __restrict__ Wc1, const float* __restrict__ bc1,
    const float* __restrict__ Wc2, const float* __restrict__ bc2,
    float* __restrict__ out, int Nn) {
  __shared__ __align__(16) float xs[TKK][TM];
  __shared__ __align__(16) float4 wsB[TKK][TN/4];
  __shared__ float red[TM][17];
  const int tid = threadIdx.x;
  const int tx = tid & 15;
  const int ty = tid >> 4;
  const int row0 = blockIdx.x * TM;
  float acc[4][8];
#pragma unroll
  for (int r = 0; r < 4; ++r)
#pragma unroll
    for (int c = 0; c < 8; ++c) acc[r][c] = 0.f;

  const int lr = tid >> 2;
  const int lk = (tid & 3) * 8;
  const int wr = tid >> 3;
  const int bb = (tid & 7) * 4;
  const int xcol = lr ^ (((lk >> 3) & 1) * 16);
  const int p0 = (tx * 2) ^ (2 * ((tx * 2) >> 3));
  const int p1 = (tx * 2 + 1) ^ (2 * ((tx * 2 + 1) >> 3));

  for (int k0 = 0; k0 < 384; k0 += TKK) {
    int row = row0 + lr; if (row >= Nn) row = Nn - 1;
    const int kg = k0 + lk;
    const int sel = kg >> 7, q = kg & 127;
    const float* aggp = (sel == 0) ? agg0 : (sel == 1) ? agg1 : agg2;
    const float* bp   = (sel == 0) ? bias0 : (sel == 1) ? bias1 : bias2;
    float4 xa = *(const float4*)(aggp + (size_t)row * 128 + q);
    float4 xb = *(const float4*)(aggp + (size_t)row * 128 + q + 4);
    float4 ba = *(const float4*)(bp + q);
    float4 bbv = *(const float4*)(bp + q + 4);
    xa.x = elu1(xa.x + ba.x); xa.y = elu1(xa.y + ba.y);
    xa.z = elu1(xa.z + ba.z); xa.w = elu1(xa.w + ba.w);
    xb.x = elu1(xb.x + bbv.x); xb.y = elu1(xb.y + bbv.y);
    xb.z = elu1(xb.z + bbv.z); xb.w = elu1(xb.w + bbv.w);
    const float4* wp = (const float4*)(Wc1 + (size_t)(k0 + wr) * TN + bb * 4);
    float4 w0 = wp[0], w1 = wp[1], w2 = wp[2], w3 = wp[3];
    __syncthreads();
    xs[lk + 0][xcol] = xa.x; xs[lk + 1][xcol] = xa.y;
    xs[lk + 2][xcol] = xa.z; xs[lk + 3][xcol] = xa.w;
    xs[lk + 4][xcol] = xb.x; xs[lk + 5][xcol] = xb.y;
    xs[lk + 6][xcol] = xb.z; xs[lk + 7][xcol] = xb.w;
    {
      int b0i = bb + 0; wsB[wr][b0i ^ (2 * (b0i >> 3))] = w0;
      int b1i = bb + 1; wsB[wr][b1i ^ (2 * (b1i >> 3))] = w1;
      int b2i = bb + 2; wsB[wr][b2i ^ (2 * (b2i >> 3))] = w2;
      int b3i = bb + 3; wsB[wr][b3i ^ (2 * (b3i >> 3))] = w3;
    }
    __syncthreads();
#pragma unroll
    for (int k = 0; k < TKK; ++k) {
      const int acol = (ty * 4) ^ (((k >> 3) & 1) * 16);
      float4 a = *(const float4*)&xs[k][acol];
      float4 b0 = wsB[k][p0];
      float4 b1 = wsB[k][p1];
      float av[4] = {a.x, a.y, a.z, a.w};
      float bv[8] = {b0.x, b0.y, b0.z, b0.w, b1.x, b1.y, b1.z, b1.w};
#pragma unroll
      for (int r = 0; r < 4; ++r)
#pragma unroll
        for (int c = 0; c < 8; ++c)
          acc[r][c] = fmaf(av[r], bv[c], acc[r][c]);
    }
  }

  float bcv[8], w2v[8];
#pragma unroll
  for (int c = 0; c < 8; ++c) {
    bcv[c] = bc1[tx * 8 + c];
    w2v[c] = Wc2[tx * 8 + c];
  }
#pragma unroll
  for (int r = 0; r < 4; ++r) {
    float p = 0.f;
#pragma unroll
    for (int c = 0; c < 8; ++c)
      p = fmaf(fmaxf(acc[r][c] + bcv[c], 0.f), w2v[c], p);
    red[ty * 4 + r][tx] = p;
  }
  __syncthreads();
  if (tid < TM) {
    float s = 0.f;
#pragma unroll
    for (int i = 0; i < 16; ++i) s += red[tid][i];
    int n = row0 + tid;
    if (n < Nn) out[n] = s + bc2[0];
  }
}

// ---------------------------------------------------------------------------
extern "C" void kernel_launch(void* const* d_in, const int* in_sizes, int n_in,
                              void* d_out, int out_size, void* d_ws, size_t ws_size,
                              hipStream_t stream) {
  const int Nn = out_size;            // 40000
  const int E0 = in_sizes[1] / 2;
  const int E1 = in_sizes[7] / 2;
  const int E2 = in_sizes[13] / 2;
  const int totE = E0 + E1 + E2;
  const int Nt = 3 * Nn;
  const int nbpc = (Nn + 127) / 128;  // buckets per category (313)
  const int NB = 3 * nbpc;            // 939

  char* base = (char*)d_ws;
  size_t off = 0;
  auto carve = [&](size_t bytes) -> void* {
    off = (off + 255) & ~(size_t)255;
    void* p = base + off;
    off += bytes;
    return p;
  };
  float* xw     = (float*)carve((size_t)Nn * 128 * 4);      // reused per cat
  float* agg3   = (float*)carve((size_t)Nt * 128 * 4);
  float* a_src3 = (float*)carve((size_t)Nt * 2 * 4);
  float* a_dst3 = (float*)carve((size_t)Nt * 2 * 4);
  int*  bktCnt  = (int*)carve((size_t)NB * SLICES * 16 * 4); // line-padded
  int2* offcnt3 = (int2*)carve((size_t)Nt * 8);
  int*  bkt     = (int*)carve((size_t)NB * BCAP * 4);
  (void)ws_size; (void)n_in;

  const int* ei0 = (const int*)d_in[1];
  const int* ei1 = (const int*)d_in[7];
  const int* ei2 = (const int*)d_in[13];

  // bucketed adjacency build
  const int ncnt = NB * SLICES * 16;
  zeroB<<<(ncnt + 255) / 256, 256, 0, stream>>>(bktCnt, ncnt);
  scatter_b<<<(totE + Nt + 255) / 256, 256, 0, stream>>>(
      ei0, ei1, ei2, E0, E1, E2, Nn, nbpc, bktCnt, bkt);
  sortbkt<<<NB, 256, 0, stream>>>(bkt, bktCnt, offcnt3, Nn, nbpc);

  for (int cat = 0; cat < 3; ++cat) {
    const float* x   = (const float*)d_in[6 * cat + 0];
    const float* W   = (const float*)d_in[6 * cat + 2];
    const float* ats = (const float*)d_in[6 * cat + 3];
    const float* atd = (const float*)d_in[6 * cat + 4];
    const int K = in_sizes[6 * cat] / Nn;
    float* a_src_c = a_src3 + (size_t)cat * Nn * 2;
    float* a_dst_c = a_dst3 + (size_t)cat * Nn * 2;

    gemm_att<<<(Nn + TM - 1) / TM, 256, 0, stream>>>(
        x, W, ats, atd, xw, a_src_c, a_dst_c, Nn, K);
    aggregate<<<((size_t)Nn * 64 + 255) / 256, 256, 0, stream>>>(
        xw, a_src_c, a_dst_c, offcnt3 + (size_t)cat * Nn, bkt,
        agg3 + (size_t)cat * Nn * 128, Nn);
  }

  final_mlp<<<(Nn + TM - 1) / TM, 256, 0, stream>>>(
      agg3, agg3 + (size_t)Nn * 128, agg3 + (size_t)2 * Nn * 128,
      (const float*)d_in[5], (const float*)d_in[11], (const float*)d_in[17],
      (const float*)d_in[18], (const float*)d_in[19],
      (const float*)d_in[20], (const float*)d_in[21],
      (float*)d_out, Nn);
}